// Round 1
// baseline (137.204 us; speedup 1.0000x reference)
//
#include <hip/hip_runtime.h>
#include <hip/hip_bf16.h>

#define NN 8192
#define DD 128
#define BB 4096

// exp(2*s) = exp2(s * 2*log2(e)) ; we use __expf(2*s) (v_mul + v_exp)
#define ROWS_PER_BLOCK 128   // 4 waves * 2 rowfrags * 16
#define COLSPLIT 8
#define COLS_PER_BLOCK (NN / COLSPLIT)   // 1024
#define COL_ITERS (COLS_PER_BLOCK / 64)  // 16

typedef __attribute__((ext_vector_type(8))) short short8;
typedef __attribute__((ext_vector_type(4))) float f32x4;

// ---- kernel 1: normalize rows, cast to bf16 -------------------------------
__global__ __launch_bounds__(64) void normalize_kernel(
    const float* __restrict__ zi, const float* __restrict__ zj,
    __hip_bfloat16* __restrict__ zn) {
  int row = blockIdx.x;
  int lane = threadIdx.x;
  const float* src = (row < BB) ? (zi + (size_t)row * DD)
                                : (zj + (size_t)(row - BB) * DD);
  float2 v = *reinterpret_cast<const float2*>(src + lane * 2);
  float ss = v.x * v.x + v.y * v.y;
  for (int m = 1; m < 64; m <<= 1) ss += __shfl_xor(ss, m, 64);
  float inv = 1.0f / fmaxf(sqrtf(ss), 1e-8f);
  __hip_bfloat16* dst = zn + (size_t)row * DD + lane * 2;
  dst[0] = __float2bfloat16(v.x * inv);
  dst[1] = __float2bfloat16(v.y * inv);
}

// ---- kernel 2: zero accumulators ------------------------------------------
__global__ __launch_bounds__(256) void zero_kernel(float* __restrict__ p) {
  p[blockIdx.x * 256 + threadIdx.x] = 0.0f;
}

// ---- kernel 3: per-row positive dot + self dot (both over bf16 data) ------
__global__ __launch_bounds__(64) void pos_kernel(
    const __hip_bfloat16* __restrict__ zn,
    float* __restrict__ posh, float* __restrict__ sd) {
  int row = blockIdx.x;
  int lane = threadIdx.x;
  int prow = row ^ BB;
  const __hip_bfloat16* ra = zn + (size_t)row * DD + lane * 2;
  const __hip_bfloat16* rb = zn + (size_t)prow * DD + lane * 2;
  float a0 = __bfloat162float(ra[0]), a1 = __bfloat162float(ra[1]);
  float b0 = __bfloat162float(rb[0]), b1 = __bfloat162float(rb[1]);
  float dp = a0 * b0 + a1 * b1;
  float sq = a0 * a0 + a1 * a1;
  for (int m = 1; m < 64; m <<= 1) {
    dp += __shfl_xor(dp, m, 64);
    sq += __shfl_xor(sq, m, 64);
  }
  if (lane == 0) {
    posh[row] = dp;  // = pos/2 (sim = 2*dot)
    sd[row] = sq;    // self dot (for diagonal exp correction)
  }
}

// ---- kernel 4: fused sim GEMM + exp-rowsum + count ------------------------
__global__ __launch_bounds__(256) void main_kernel(
    const __hip_bfloat16* __restrict__ zn, const float* __restrict__ posh,
    float* __restrict__ rowsum, float* __restrict__ rowcnt) {
  int w = threadIdx.x >> 6;
  int lane = threadIdx.x & 63;
  int lo = lane & 15, hi = lane >> 4;
  int rowBase = blockIdx.x * ROWS_PER_BLOCK;
  int colBase = blockIdx.y * COLS_PER_BLOCK;

  const short* znS = reinterpret_cast<const short*>(zn);

  // A fragments: 2 row-frags x 4 k-chunks, held in registers whole kernel.
  // A layout (16x16x32): row = lane&15, k = 8*(lane>>4)+e (+32*chunk)
  short8 a[2][4];
  for (int rf = 0; rf < 2; ++rf) {
    int arow = rowBase + 32 * w + 16 * rf + lo;
    const short* p = znS + (size_t)arow * DD + 8 * hi;
    for (int c = 0; c < 4; ++c)
      a[rf][c] = *reinterpret_cast<const short8*>(p + 32 * c);
  }

  float posv[2][4];
  float sume[2][4];
  float cntv[2][4];
  for (int rf = 0; rf < 2; ++rf)
    for (int r = 0; r < 4; ++r) {
      // C/D layout: col = lane&15, row = 4*(lane>>4)+reg  [m89/m91]
      posv[rf][r] = posh[rowBase + 32 * w + 16 * rf + 4 * hi + r];
      sume[rf][r] = 0.0f;
      cntv[rf][r] = 0.0f;
    }

  for (int it = 0; it < COL_ITERS; ++it) {
    int col0 = colBase + 64 * it;
    for (int cf = 0; cf < 4; ++cf) {
      int bcol = col0 + 16 * cf + lo;
      const short* p = znS + (size_t)bcol * DD + 8 * hi;
      short8 b[4];
      for (int c = 0; c < 4; ++c)
        b[c] = *reinterpret_cast<const short8*>(p + 32 * c);
      for (int rf = 0; rf < 2; ++rf) {
        f32x4 acc = {0.0f, 0.0f, 0.0f, 0.0f};
        for (int c = 0; c < 4; ++c)
          acc = __builtin_amdgcn_mfma_f32_16x16x32_bf16(a[rf][c], b[c], acc,
                                                        0, 0, 0);
        for (int r = 0; r < 4; ++r) {
          float s = acc[r];               // dot (= sim/2)
          sume[rf][r] += __expf(s + s);   // exp(sim)
          cntv[rf][r] += (posv[rf][r] > s) ? 1.0f : 0.0f;
        }
      }
    }
  }

  // reduce across the 16 lanes (bits 0..3) that share a row
  for (int rf = 0; rf < 2; ++rf)
    for (int r = 0; r < 4; ++r) {
      float v = sume[rf][r];
      float c2 = cntv[rf][r];
      for (int m = 1; m < 16; m <<= 1) {
        v += __shfl_xor(v, m, 64);
        c2 += __shfl_xor(c2, m, 64);
      }
      if (lo == 0) {
        int row = rowBase + 32 * w + 16 * rf + 4 * hi + r;
        atomicAdd(&rowsum[row], v);
        atomicAdd(&rowcnt[row], c2);
      }
    }
}

// ---- kernel 5: finalize ----------------------------------------------------
__global__ __launch_bounds__(256) void finalize_kernel(
    const float* __restrict__ rowsum, const float* __restrict__ rowcnt,
    const float* __restrict__ posh, const float* __restrict__ sd,
    float* __restrict__ out) {
  int tid = threadIdx.x;
  float lsum = 0.0f;
  unsigned int csum = 0;
  for (int i = tid; i < NN; i += 256) {
    float diag = __expf(sd[i] + sd[i]);       // exp(sim_ii)
    float lse = logf(rowsum[i] - diag);       // exclude diagonal
    lsum += lse - 2.0f * posh[i];             // lse_i - pos_i
    csum += (unsigned int)rowcnt[i];
  }
  for (int m = 1; m < 64; m <<= 1) {
    lsum += __shfl_xor(lsum, m, 64);
    csum += __shfl_xor(csum, m, 64);
  }
  __shared__ float ls[4];
  __shared__ unsigned int cs[4];
  int w = tid >> 6, lane = tid & 63;
  if (lane == 0) { ls[w] = lsum; cs[w] = csum; }
  __syncthreads();
  if (tid == 0) {
    float L = ls[0] + ls[1] + ls[2] + ls[3];
    unsigned long long C = (unsigned long long)cs[0] + cs[1] + cs[2] + cs[3];
    out[0] = L / (float)NN;
    out[1] = (float)((double)C / ((double)NN * (double)NN));
  }
}

extern "C" void kernel_launch(void* const* d_in, const int* in_sizes, int n_in,
                              void* d_out, int out_size, void* d_ws,
                              size_t ws_size, hipStream_t stream) {
  const float* zi = (const float*)d_in[0];
  const float* zj = (const float*)d_in[1];
  float* out = (float*)d_out;

  __hip_bfloat16* zn = (__hip_bfloat16*)d_ws;                  // 2 MB
  float* posh = (float*)((char*)d_ws + (size_t)NN * DD * 2);   // 32 KB
  float* sd = posh + NN;
  float* rowsum = sd + NN;
  float* rowcnt = rowsum + NN;

  normalize_kernel<<<NN, 64, 0, stream>>>(zi, zj, zn);
  zero_kernel<<<(2 * NN) / 256, 256, 0, stream>>>(rowsum);  // rowsum+rowcnt
  pos_kernel<<<NN, 64, 0, stream>>>(zn, posh, sd);
  main_kernel<<<dim3(NN / ROWS_PER_BLOCK, COLSPLIT), 256, 0, stream>>>(
      zn, posh, rowsum, rowcnt);
  finalize_kernel<<<1, 256, 0, stream>>>(rowsum, rowcnt, posh, sd, out);
}